// Round 1
// baseline (1142.540 us; speedup 1.0000x reference)
//
#include <hip/hip_runtime.h>
#include <math.h>

#define T_TOK 8192
#define HD    2048
#define NE    8
#define BM    128
#define BN    128
#define BK    32
#define MAXT  136            // max row-tiles: 16384/128 + 8 pad tiles
#define RMAX  17408          // 16384 + 8*128 padding

typedef __bf16 bf16x8 __attribute__((ext_vector_type(8)));
typedef float  f32x4  __attribute__((ext_vector_type(4)));

// ---------------------------------------------------------------------------
// Router: one wave per token. fp32 logits (exact), top-2, renormalized weights.
// ---------------------------------------------------------------------------
__global__ __launch_bounds__(256) void router_kernel(
    const float* __restrict__ x, const float* __restrict__ Wg,
    const float* __restrict__ bg, float* __restrict__ logits_out,
    int* __restrict__ cnt, int* __restrict__ tok_exp, float* __restrict__ tok_w)
{
    const int lane = threadIdx.x & 63;
    const int wv   = threadIdx.x >> 6;
    const int t    = blockIdx.x * 4 + wv;
    const float* xr = x + (size_t)t * HD;

    float acc[8] = {0.f,0.f,0.f,0.f,0.f,0.f,0.f,0.f};
    for (int h0 = 0; h0 < HD; h0 += 64) {
        float xv = xr[h0 + lane];
        const float4* wg = reinterpret_cast<const float4*>(Wg + (size_t)(h0 + lane) * NE);
        float4 wa = wg[0], wb = wg[1];
        acc[0] += xv * wa.x; acc[1] += xv * wa.y;
        acc[2] += xv * wa.z; acc[3] += xv * wa.w;
        acc[4] += xv * wb.x; acc[5] += xv * wb.y;
        acc[6] += xv * wb.z; acc[7] += xv * wb.w;
    }
#pragma unroll
    for (int off = 32; off; off >>= 1) {
#pragma unroll
        for (int e = 0; e < 8; ++e) acc[e] += __shfl_xor(acc[e], off);
    }
    if (lane == 0) {
        float lg[8];
#pragma unroll
        for (int e = 0; e < 8; ++e) lg[e] = acc[e] + bg[e];
        float4* lo = reinterpret_cast<float4*>(logits_out + (size_t)t * NE);
        lo[0] = make_float4(lg[0], lg[1], lg[2], lg[3]);
        lo[1] = make_float4(lg[4], lg[5], lg[6], lg[7]);
        // top-2, ties -> lowest index first (jax.lax.top_k semantics)
        int i0 = 0;
        for (int e = 1; e < 8; ++e) if (lg[e] > lg[i0]) i0 = e;
        int i1 = (i0 == 0) ? 1 : 0;
        for (int e = 0; e < 8; ++e) if (e != i0 && lg[e] > lg[i1]) i1 = e;
        // renormalized top-2 softmax weights
        float d = expf(lg[i1] - lg[i0]);   // <= 1
        float inv = 1.0f / (1.0f + d);
        tok_exp[t * 2]     = i0;
        tok_exp[t * 2 + 1] = i1;
        tok_w[t * 2]       = inv;
        tok_w[t * 2 + 1]   = d * inv;
        atomicAdd(&cnt[i0], 1);
        atomicAdd(&cnt[i1], 1);
    }
}

// ---------------------------------------------------------------------------
// Scan: padded per-expert offsets, tile table, -1-fill row_token, init cursors.
// ---------------------------------------------------------------------------
__global__ void scan_kernel(const int* __restrict__ cnt, int* __restrict__ cursor,
                            int* __restrict__ tile_exp, int* __restrict__ tile_row0,
                            int* __restrict__ ntiles, int* __restrict__ row_token)
{
    for (int i = threadIdx.x; i < RMAX; i += blockDim.x) row_token[i] = -1;
    if (threadIdx.x == 0) {
        int off = 0, nt = 0;
        for (int e = 0; e < NE; ++e) {
            cursor[e] = off;
            int c = cnt[e];
            int tiles = (c + BM - 1) >> 7;
            for (int i = 0; i < tiles; ++i) {
                tile_exp[nt]  = e;
                tile_row0[nt] = off + (i << 7);
                ++nt;
            }
            off += tiles << 7;
        }
        *ntiles = nt;
    }
}

// ---------------------------------------------------------------------------
// Scatter: (token, slot) -> permuted row arrays (unstable order; results are
// order-independent: per-row GEMM is identical and the 2-way atomic fp add is
// commutative).
// ---------------------------------------------------------------------------
__global__ __launch_bounds__(256) void scatter_kernel(
    const int* __restrict__ tok_exp, const float* __restrict__ tok_w,
    int* __restrict__ cursor, int* __restrict__ row_token, float* __restrict__ row_coef)
{
    int t = blockIdx.x * blockDim.x + threadIdx.x;
    if (t >= T_TOK) return;
#pragma unroll
    for (int k = 0; k < 2; ++k) {
        int e = tok_exp[t * 2 + k];
        int pos = atomicAdd(&cursor[e], 1);
        row_token[pos] = t;
        row_coef[pos]  = tok_w[t * 2 + k];
    }
}

// ---------------------------------------------------------------------------
// Grouped GEMM: per row-tile (one expert) x col-tile. 128x128 tile, 4 waves,
// mfma_f32_16x16x32_bf16, fp32->bf16 on the fly. W (K-major) transposed via a
// bank-swizzled fp32 LDS staging buffer. Epilogue: (acc + b[e][f]) * coef,
// atomicAdd into out.
// ---------------------------------------------------------------------------
#define STG_IDX(k, f) ((k) * 132 + ((f) ^ (((k) & 7) << 2)))

__global__ __launch_bounds__(256) void moe_gemm(
    const float* __restrict__ x, const float* __restrict__ W,
    const float* __restrict__ bexp,
    const int* __restrict__ tile_exp, const int* __restrict__ tile_row0,
    const int* __restrict__ ntiles_p, const int* __restrict__ row_token,
    const float* __restrict__ row_coef, float* __restrict__ out)
{
    const int rt = blockIdx.y;
    if (rt >= *ntiles_p) return;
    const int e  = tile_exp[rt];
    const int r0 = tile_row0[rt];
    const int cb = blockIdx.x * BN;

    __shared__ __align__(16) __bf16 Alds[BM][BK + 8];   // +8 pad: 80B row stride
    __shared__ __align__(16) __bf16 Blds[BN][BK + 8];   // [f][k], transposed
    __shared__ __align__(16) float  stage[BK * 132];    // fp32 W tile [k][f], swizzled

    const int tid  = threadIdx.x;
    const int lane = tid & 63;
    const int wv   = tid >> 6;
    const int wr   = (wv >> 1) * 64;   // wave row base in tile
    const int wc   = (wv & 1) * 64;    // wave col base in tile

    // A staging: 2 threads per row, 16 fp32 each
    const int arow  = tid >> 1;
    const int acol0 = (tid & 1) * 16;
    const int tokA  = row_token[r0 + arow];
    const float* aptr = x + (size_t)(tokA < 0 ? 0 : tokA) * HD + acol0;

    // W staging: 8 threads per k-row, 16 fp32 each (coalesced)
    const int wk  = tid >> 3;
    const int wf0 = (tid & 7) * 16;
    const float* wptr = W + (size_t)e * HD * HD + (size_t)wk * HD + cb + wf0;

    // transpose: 2 threads per f-column, 16 k each
    const int bn  = tid >> 1;
    const int bk0 = (tid & 1) * 16;

    f32x4 acc[4][4];
#pragma unroll
    for (int m = 0; m < 4; ++m)
#pragma unroll
        for (int n = 0; n < 4; ++n) acc[m][n] = (f32x4){0.f, 0.f, 0.f, 0.f};

    const int fr = lane & 15;
    const int fk = (lane >> 4) * 8;

    for (int k0 = 0; k0 < HD; k0 += BK) {
        // ---- global loads (overlap previous compute) ----
        float4 av[4];
#pragma unroll
        for (int j = 0; j < 4; ++j) av[j] = make_float4(0.f, 0.f, 0.f, 0.f);
        if (tokA >= 0) {
            const float4* ap = reinterpret_cast<const float4*>(aptr + k0);
#pragma unroll
            for (int j = 0; j < 4; ++j) av[j] = ap[j];
        }
        const float4* wp = reinterpret_cast<const float4*>(wptr + (size_t)k0 * HD);
        float4 wvv[4];
#pragma unroll
        for (int j = 0; j < 4; ++j) wvv[j] = wp[j];

        __syncthreads();   // previous compute done reading LDS

        // ---- A tile: cvt -> bf16, contiguous writes ----
        {
            bf16x8 p0, p1;
            p0[0]=(__bf16)av[0].x; p0[1]=(__bf16)av[0].y; p0[2]=(__bf16)av[0].z; p0[3]=(__bf16)av[0].w;
            p0[4]=(__bf16)av[1].x; p0[5]=(__bf16)av[1].y; p0[6]=(__bf16)av[1].z; p0[7]=(__bf16)av[1].w;
            p1[0]=(__bf16)av[2].x; p1[1]=(__bf16)av[2].y; p1[2]=(__bf16)av[2].z; p1[3]=(__bf16)av[2].w;
            p1[4]=(__bf16)av[3].x; p1[5]=(__bf16)av[3].y; p1[6]=(__bf16)av[3].z; p1[7]=(__bf16)av[3].w;
            *reinterpret_cast<bf16x8*>(&Alds[arow][acol0])     = p0;
            *reinterpret_cast<bf16x8*>(&Alds[arow][acol0 + 8]) = p1;
        }
        // ---- W tile: fp32 into swizzled stage ----
#pragma unroll
        for (int j = 0; j < 4; ++j)
            *reinterpret_cast<float4*>(&stage[STG_IDX(wk, wf0 + j * 4)]) = wvv[j];

        __syncthreads();

        // ---- transpose stage -> Blds[f][k] (bf16) ----
        {
            bf16x8 q0, q1;
#pragma unroll
            for (int j = 0; j < 8; ++j) q0[j] = (__bf16)stage[STG_IDX(bk0 + j, bn)];
#pragma unroll
            for (int j = 0; j < 8; ++j) q1[j] = (__bf16)stage[STG_IDX(bk0 + 8 + j, bn)];
            *reinterpret_cast<bf16x8*>(&Blds[bn][bk0])     = q0;
            *reinterpret_cast<bf16x8*>(&Blds[bn][bk0 + 8]) = q1;
        }

        __syncthreads();

        // ---- fragments + MFMA ----
        bf16x8 amv[4], bnv[4];
#pragma unroll
        for (int m = 0; m < 4; ++m)
            amv[m] = *reinterpret_cast<const bf16x8*>(&Alds[wr + m * 16 + fr][fk]);
#pragma unroll
        for (int n = 0; n < 4; ++n)
            bnv[n] = *reinterpret_cast<const bf16x8*>(&Blds[wc + n * 16 + fr][fk]);
#pragma unroll
        for (int m = 0; m < 4; ++m)
#pragma unroll
            for (int n = 0; n < 4; ++n)
                acc[m][n] = __builtin_amdgcn_mfma_f32_16x16x32_bf16(amv[m], bnv[n], acc[m][n], 0, 0, 0);
    }

    // ---- epilogue: (acc + bias) * coef, atomic combine (2 adds/element) ----
    const int rj = (lane >> 4) * 4;
#pragma unroll
    for (int m = 0; m < 4; ++m) {
        const int lr = wr + m * 16 + rj;
        int tok[4]; float cf[4];
#pragma unroll
        for (int j = 0; j < 4; ++j) {
            tok[j] = row_token[r0 + lr + j];
            cf[j]  = row_coef[r0 + lr + j];
        }
#pragma unroll
        for (int n = 0; n < 4; ++n) {
            const int f = cb + wc + n * 16 + fr;
            const float bias = bexp[(size_t)e * HD + f];
#pragma unroll
            for (int j = 0; j < 4; ++j) {
                if (tok[j] >= 0)
                    atomicAdd(&out[(size_t)tok[j] * HD + f], (acc[m][n][j] + bias) * cf[j]);
            }
        }
    }
}

// ---------------------------------------------------------------------------
extern "C" void kernel_launch(void* const* d_in, const int* in_sizes, int n_in,
                              void* d_out, int out_size, void* d_ws, size_t ws_size,
                              hipStream_t stream)
{
    (void)in_sizes; (void)n_in; (void)out_size; (void)ws_size;

    const float* x  = (const float*)d_in[0];
    const float* Wg = (const float*)d_in[1];
    const float* bg = (const float*)d_in[2];
    const float* W  = (const float*)d_in[3];
    const float* b  = (const float*)d_in[4];
    // d_in[5] = topk (hard-coded 2 below)

    float* out    = (float*)d_out;
    float* logits = out + (size_t)T_TOK * HD;

    // workspace layout (~280 KB)
    char* p = (char*)d_ws;
    int*   cnt       = (int*)p;   p += NE * 4;
    int*   cursor    = (int*)p;   p += NE * 4;
    int*   ntiles    = (int*)p;   p += 8;              // keep 8B alignment
    int*   tile_exp  = (int*)p;   p += MAXT * 4;
    int*   tile_row0 = (int*)p;   p += MAXT * 4;
    int*   tok_exp   = (int*)p;   p += T_TOK * 2 * 4;
    float* tok_w     = (float*)p; p += T_TOK * 2 * 4;
    int*   row_token = (int*)p;   p += RMAX * 4;
    float* row_coef  = (float*)p; p += RMAX * 4;

    hipMemsetAsync(cnt, 0, NE * 4, stream);
    hipMemsetAsync(out, 0, (size_t)T_TOK * HD * sizeof(float), stream);

    router_kernel<<<T_TOK / 4, 256, 0, stream>>>(x, Wg, bg, logits, cnt, tok_exp, tok_w);
    scan_kernel<<<1, 256, 0, stream>>>(cnt, cursor, tile_exp, tile_row0, ntiles, row_token);
    scatter_kernel<<<T_TOK / 256, 256, 0, stream>>>(tok_exp, tok_w, cursor, row_token, row_coef);

    dim3 grid(HD / BN, MAXT);
    moe_gemm<<<grid, 256, 0, stream>>>(x, W, b, tile_exp, tile_row0, ntiles,
                                       row_token, row_coef, out);
}

// Round 2
// 674.341 us; speedup vs baseline: 1.6943x; 1.6943x over previous
//
#include <hip/hip_runtime.h>
#include <math.h>

#define T_TOK 8192
#define HD    2048
#define NE    8
#define BM    128
#define BN    128
#define MAXT  136            // max row-tiles: 16384/128 + 8 pad tiles
#define RMAX  17408          // 16384 + 8*128 padding

typedef __bf16 bf16x8 __attribute__((ext_vector_type(8)));
typedef float  f32x4  __attribute__((ext_vector_type(4)));

// 16B async global->LDS. LDS dest is wave-uniform base + lane*16 (linear);
// per-lane GLOBAL source carries the swizzle (rule 21: linear dest +
// inverse-swizzled source + swizzled read).
#define GLOAD16(src, dst)                                                              \
    __builtin_amdgcn_global_load_lds((__attribute__((address_space(1))) void*)(src),   \
                                     (__attribute__((address_space(3))) void*)(dst),   \
                                     16, 0, 0)

// ---------------------------------------------------------------------------
// Router: one wave per token. fp32 logits (exact), top-2, renormalized weights.
// ---------------------------------------------------------------------------
__global__ __launch_bounds__(256) void router_kernel(
    const float* __restrict__ x, const float* __restrict__ Wg,
    const float* __restrict__ bg, float* __restrict__ logits_out,
    int* __restrict__ cnt, int* __restrict__ tok_exp, float* __restrict__ tok_w)
{
    const int lane = threadIdx.x & 63;
    const int wv   = threadIdx.x >> 6;
    const int t    = blockIdx.x * 4 + wv;
    const float* xr = x + (size_t)t * HD;

    float acc[8] = {0.f,0.f,0.f,0.f,0.f,0.f,0.f,0.f};
    for (int h0 = 0; h0 < HD; h0 += 64) {
        float xv = xr[h0 + lane];
        const float4* wg = reinterpret_cast<const float4*>(Wg + (size_t)(h0 + lane) * NE);
        float4 wa = wg[0], wb = wg[1];
        acc[0] += xv * wa.x; acc[1] += xv * wa.y;
        acc[2] += xv * wa.z; acc[3] += xv * wa.w;
        acc[4] += xv * wb.x; acc[5] += xv * wb.y;
        acc[6] += xv * wb.z; acc[7] += xv * wb.w;
    }
#pragma unroll
    for (int off = 32; off; off >>= 1) {
#pragma unroll
        for (int e = 0; e < 8; ++e) acc[e] += __shfl_xor(acc[e], off);
    }
    if (lane == 0) {
        float lg[8];
#pragma unroll
        for (int e = 0; e < 8; ++e) lg[e] = acc[e] + bg[e];
        float4* lo = reinterpret_cast<float4*>(logits_out + (size_t)t * NE);
        lo[0] = make_float4(lg[0], lg[1], lg[2], lg[3]);
        lo[1] = make_float4(lg[4], lg[5], lg[6], lg[7]);
        int i0 = 0;
        for (int e = 1; e < 8; ++e) if (lg[e] > lg[i0]) i0 = e;
        int i1 = (i0 == 0) ? 1 : 0;
        for (int e = 0; e < 8; ++e) if (e != i0 && lg[e] > lg[i1]) i1 = e;
        float d = expf(lg[i1] - lg[i0]);
        float inv = 1.0f / (1.0f + d);
        tok_exp[t * 2]     = i0;
        tok_exp[t * 2 + 1] = i1;
        tok_w[t * 2]       = inv;
        tok_w[t * 2 + 1]   = d * inv;
        atomicAdd(&cnt[i0], 1);
        atomicAdd(&cnt[i1], 1);
    }
}

// ---------------------------------------------------------------------------
// x fp32 -> bf16 (linear copy)
// ---------------------------------------------------------------------------
__global__ __launch_bounds__(256) void cvt_x_kernel(const float* __restrict__ x,
                                                    __bf16* __restrict__ xb)
{
    size_t i = ((size_t)blockIdx.x * 256 + threadIdx.x) * 8;
    const float4* p = reinterpret_cast<const float4*>(x + i);
    float4 a = p[0], b = p[1];
    bf16x8 v;
    v[0]=(__bf16)a.x; v[1]=(__bf16)a.y; v[2]=(__bf16)a.z; v[3]=(__bf16)a.w;
    v[4]=(__bf16)b.x; v[5]=(__bf16)b.y; v[6]=(__bf16)b.z; v[7]=(__bf16)b.w;
    *reinterpret_cast<bf16x8*>(xb + i) = v;
}

// ---------------------------------------------------------------------------
// W[e][k][f] fp32 -> Wt[e][f][k] bf16 (64x64 LDS tile transpose)
// ---------------------------------------------------------------------------
__global__ __launch_bounds__(256) void wt_kernel(const float* __restrict__ W,
                                                 __bf16* __restrict__ Wt)
{
    const int e  = blockIdx.z;
    const int k0 = blockIdx.y * 64;
    const int f0 = blockIdx.x * 64;
    __shared__ __bf16 T[64][80];            // 160B row pitch, 16B-aligned rows

    const int t  = threadIdx.x;
    const int fi = (t & 15) * 4;
    const int kb = t >> 4;                   // 0..15
    const float* src = W + (size_t)e * HD * HD + (size_t)(k0 + kb) * HD + f0 + fi;
#pragma unroll
    for (int j = 0; j < 4; ++j) {
        float4 v = *reinterpret_cast<const float4*>(src + (size_t)j * 16 * HD);
        int k = kb + j * 16;
        T[fi + 0][k] = (__bf16)v.x;
        T[fi + 1][k] = (__bf16)v.y;
        T[fi + 2][k] = (__bf16)v.z;
        T[fi + 3][k] = (__bf16)v.w;
    }
    __syncthreads();
    const int kc = (t & 7) * 8;
    const int fr = t >> 3;                   // 0..31
#pragma unroll
    for (int j = 0; j < 2; ++j) {
        int f = fr + j * 32;
        bf16x8 v = *reinterpret_cast<const bf16x8*>(&T[f][kc]);
        *reinterpret_cast<bf16x8*>(Wt + (size_t)e * HD * HD + (size_t)(f0 + f) * HD + k0 + kc) = v;
    }
}

// ---------------------------------------------------------------------------
// Scan: padded per-expert offsets, tile table, init cursors.
// (row_token pre-filled to -1 via hipMemsetAsync(0xFF))
// ---------------------------------------------------------------------------
__global__ void scan_kernel(const int* __restrict__ cnt, int* __restrict__ cursor,
                            int* __restrict__ tile_exp, int* __restrict__ tile_row0,
                            int* __restrict__ ntiles)
{
    if (threadIdx.x == 0) {
        int off = 0, nt = 0;
        for (int e = 0; e < NE; ++e) {
            cursor[e] = off;
            int c = cnt[e];
            int tiles = (c + BM - 1) >> 7;
            for (int i = 0; i < tiles; ++i) {
                tile_exp[nt]  = e;
                tile_row0[nt] = off + (i << 7);
                ++nt;
            }
            off += tiles << 7;
        }
        *ntiles = nt;
    }
}

// ---------------------------------------------------------------------------
// Scatter: (token, slot) -> permuted row arrays (order-independent results).
// ---------------------------------------------------------------------------
__global__ __launch_bounds__(256) void scatter_kernel(
    const int* __restrict__ tok_exp, const float* __restrict__ tok_w,
    int* __restrict__ cursor, int* __restrict__ row_token, float* __restrict__ row_coef)
{
    int t = blockIdx.x * blockDim.x + threadIdx.x;
    if (t >= T_TOK) return;
#pragma unroll
    for (int k = 0; k < 2; ++k) {
        int e = tok_exp[t * 2 + k];
        int pos = atomicAdd(&cursor[e], 1);
        row_token[pos] = t;
        row_coef[pos]  = tok_w[t * 2 + k];
    }
}

// ---------------------------------------------------------------------------
// Fast grouped GEMM (m97 structure): 128x128 tile, BK=64, 4 waves,
// global_load_lds x16B for A (gathered rows of xb) and B (Wt rows), XOR-swizzle
// via pre-swizzled global source + swizzled ds_read_b128. 2 barriers/K-step.
// ---------------------------------------------------------------------------
__global__ __launch_bounds__(256) void moe_gemm_fast(
    const __bf16* __restrict__ xb, const __bf16* __restrict__ Wt,
    const float* __restrict__ bexp,
    const int* __restrict__ tile_exp, const int* __restrict__ tile_row0,
    const int* __restrict__ ntiles_p, const int* __restrict__ row_token,
    const float* __restrict__ row_coef, float* __restrict__ out)
{
    const int rt = blockIdx.y;
    if (rt >= *ntiles_p) return;
    const int e  = tile_exp[rt];
    const int r0 = tile_row0[rt];
    const int cb = blockIdx.x * BN;

    __shared__ __align__(16) __bf16 Albuf[BM * 64];   // 16 KB, linear [row][k]
    __shared__ __align__(16) __bf16 Blbuf[BN * 64];   // 16 KB, linear [f][k]

    const int tid  = threadIdx.x;
    const int lane = tid & 63;
    const int wv   = tid >> 6;
    const int wr   = (wv >> 1) * 64;
    const int wc   = (wv & 1) * 64;

    // Source column pre-swizzle: dest byte o = i*4096 + tid*16, row = o>>7 =
    // i*32 + (tid>>3); (row&7) = (tid>>3)&7 (i*32 ≡ 0 mod 8) -> issue-invariant.
    const int colA = (((tid & 7) * 16) ^ (((tid >> 3) & 7) << 4)) >> 1;  // bf16 elems

    const __bf16* srcA[4];
    const __bf16* srcB[4];
#pragma unroll
    for (int i = 0; i < 4; ++i) {
        int r   = i * 32 + (tid >> 3);
        int tok = row_token[r0 + r];
        if (tok < 0) tok = 0;                 // pad rows: load row 0, discarded later
        srcA[i] = xb + (size_t)tok * HD + colA;
        srcB[i] = Wt + ((size_t)e << 22) + (size_t)(cb + r) * HD + colA;
    }
    char* ldsA = (char*)Albuf + wv * 1024;    // wave-uniform LDS bases
    char* ldsB = (char*)Blbuf + wv * 1024;

    f32x4 acc[4][4];
#pragma unroll
    for (int m = 0; m < 4; ++m)
#pragma unroll
        for (int n = 0; n < 4; ++n) acc[m][n] = (f32x4){0.f, 0.f, 0.f, 0.f};

    const int fr = lane & 15;
    const int fk = (lane >> 4) * 8;

    for (int k0 = 0; k0 < HD; k0 += 64) {
        __syncthreads();                      // prev frag reads done
#pragma unroll
        for (int i = 0; i < 4; ++i) GLOAD16(srcA[i] + k0, ldsA + i * 4096);
#pragma unroll
        for (int i = 0; i < 4; ++i) GLOAD16(srcB[i] + k0, ldsB + i * 4096);
        __syncthreads();                      // loads landed (vmcnt(0) drain)

#pragma unroll
        for (int ks = 0; ks < 2; ++ks) {
            bf16x8 amv[4], bnv[4];
#pragma unroll
            for (int m = 0; m < 4; ++m) {
                int row  = wr + m * 16 + fr;
                int byte = (row << 7) + ((ks * 32 + fk) << 1);
                byte ^= (row & 7) << 4;
                amv[m] = *reinterpret_cast<const bf16x8*>((const char*)Albuf + byte);
            }
#pragma unroll
            for (int n = 0; n < 4; ++n) {
                int row  = wc + n * 16 + fr;
                int byte = (row << 7) + ((ks * 32 + fk) << 1);
                byte ^= (row & 7) << 4;
                bnv[n] = *reinterpret_cast<const bf16x8*>((const char*)Blbuf + byte);
            }
#pragma unroll
            for (int m = 0; m < 4; ++m)
#pragma unroll
                for (int n = 0; n < 4; ++n)
                    acc[m][n] = __builtin_amdgcn_mfma_f32_16x16x32_bf16(amv[m], bnv[n], acc[m][n], 0, 0, 0);
        }
    }

    // epilogue: (acc + bias) * coef, atomic combine (2 adds/element)
    const int rj = (lane >> 4) * 4;
#pragma unroll
    for (int m = 0; m < 4; ++m) {
        const int lr = wr + m * 16 + rj;
        int tok[4]; float cf[4];
#pragma unroll
        for (int j = 0; j < 4; ++j) {
            tok[j] = row_token[r0 + lr + j];
            cf[j]  = row_coef[r0 + lr + j];
        }
#pragma unroll
        for (int n = 0; n < 4; ++n) {
            const int f = cb + wc + n * 16 + fr;
            const float bias = bexp[(size_t)e * HD + f];
#pragma unroll
            for (int j = 0; j < 4; ++j) {
                if (tok[j] >= 0)
                    atomicAdd(&out[(size_t)tok[j] * HD + f], (acc[m][n][j] + bias) * cf[j]);
            }
        }
    }
}

// ---------------------------------------------------------------------------
// Fallback grouped GEMM (round-1 kernel, fp32 inputs, per-tile transpose) —
// used only if ws_size can't hold the bf16 staging buffers.
// ---------------------------------------------------------------------------
#define STG_IDX(k, f) ((k) * 132 + ((f) ^ (((k) & 7) << 2)))

__global__ __launch_bounds__(256) void moe_gemm(
    const float* __restrict__ x, const float* __restrict__ W,
    const float* __restrict__ bexp,
    const int* __restrict__ tile_exp, const int* __restrict__ tile_row0,
    const int* __restrict__ ntiles_p, const int* __restrict__ row_token,
    const float* __restrict__ row_coef, float* __restrict__ out)
{
    const int rt = blockIdx.y;
    if (rt >= *ntiles_p) return;
    const int e  = tile_exp[rt];
    const int r0 = tile_row0[rt];
    const int cb = blockIdx.x * BN;

    __shared__ __align__(16) __bf16 Alds[BM][40];
    __shared__ __align__(16) __bf16 Blds[BN][40];
    __shared__ __align__(16) float  stage[32 * 132];

    const int tid  = threadIdx.x;
    const int lane = tid & 63;
    const int wv   = tid >> 6;
    const int wr   = (wv >> 1) * 64;
    const int wc   = (wv & 1) * 64;

    const int arow  = tid >> 1;
    const int acol0 = (tid & 1) * 16;
    const int tokA  = row_token[r0 + arow];
    const float* aptr = x + (size_t)(tokA < 0 ? 0 : tokA) * HD + acol0;

    const int wk  = tid >> 3;
    const int wf0 = (tid & 7) * 16;
    const float* wptr = W + (size_t)e * HD * HD + (size_t)wk * HD + cb + wf0;

    const int bn  = tid >> 1;
    const int bk0 = (tid & 1) * 16;

    f32x4 acc[4][4];
#pragma unroll
    for (int m = 0; m < 4; ++m)
#pragma unroll
        for (int n = 0; n < 4; ++n) acc[m][n] = (f32x4){0.f, 0.f, 0.f, 0.f};

    const int fr = lane & 15;
    const int fk = (lane >> 4) * 8;

    for (int k0 = 0; k0 < HD; k0 += 32) {
        float4 av[4];
#pragma unroll
        for (int j = 0; j < 4; ++j) av[j] = make_float4(0.f, 0.f, 0.f, 0.f);
        if (tokA >= 0) {
            const float4* ap = reinterpret_cast<const float4*>(aptr + k0);
#pragma unroll
            for (int j = 0; j < 4; ++j) av[j] = ap[j];
        }
        const float4* wp = reinterpret_cast<const float4*>(wptr + (size_t)k0 * HD);
        float4 wvv[4];
#pragma unroll
        for (int j = 0; j < 4; ++j) wvv[j] = wp[j];

        __syncthreads();
        {
            bf16x8 p0, p1;
            p0[0]=(__bf16)av[0].x; p0[1]=(__bf16)av[0].y; p0[2]=(__bf16)av[0].z; p0[3]=(__bf16)av[0].w;
            p0[4]=(__bf16)av[1].x; p0[5]=(__bf16)av[1].y; p0[6]=(__bf16)av[1].z; p0[7]=(__bf16)av[1].w;
            p1[0]=(__bf16)av[2].x; p1[1]=(__bf16)av[2].y; p1[2]=(__bf16)av[2].z; p1[3]=(__bf16)av[2].w;
            p1[4]=(__bf16)av[3].x; p1[5]=(__bf16)av[3].y; p1[6]=(__bf16)av[3].z; p1[7]=(__bf16)av[3].w;
            *reinterpret_cast<bf16x8*>(&Alds[arow][acol0])     = p0;
            *reinterpret_cast<bf16x8*>(&Alds[arow][acol0 + 8]) = p1;
        }
#pragma unroll
        for (int j = 0; j < 4; ++j)
            *reinterpret_cast<float4*>(&stage[STG_IDX(wk, wf0 + j * 4)]) = wvv[j];

        __syncthreads();
        {
            bf16x8 q0, q1;
#pragma unroll
            for (int j = 0; j < 8; ++j) q0[j] = (__bf16)stage[STG_IDX(bk0 + j, bn)];
#pragma unroll
            for (int j = 0; j < 8; ++j) q1[j] = (__bf16)stage[STG_IDX(bk0 + 8 + j, bn)];
            *reinterpret_cast<bf16x8*>(&Blds[bn][bk0])     = q0;
            *reinterpret_cast<bf16x8*>(&Blds[bn][bk0 + 8]) = q1;
        }
        __syncthreads();

        bf16x8 amv[4], bnv[4];
#pragma unroll
        for (int m = 0; m < 4; ++m)
            amv[m] = *reinterpret_cast<const bf16x8*>(&Alds[wr + m * 16 + fr][fk]);
#pragma unroll
        for (int n = 0; n < 4; ++n)
            bnv[n] = *reinterpret_cast<const bf16x8*>(&Blds[wc + n * 16 + fr][fk]);
#pragma unroll
        for (int m = 0; m < 4; ++m)
#pragma unroll
            for (int n = 0; n < 4; ++n)
                acc[m][n] = __builtin_amdgcn_mfma_f32_16x16x32_bf16(amv[m], bnv[n], acc[m][n], 0, 0, 0);
    }

    const int rj = (lane >> 4) * 4;
#pragma unroll
    for (int m = 0; m < 4; ++m) {
        const int lr = wr + m * 16 + rj;
        int tok[4]; float cf[4];
#pragma unroll
        for (int j = 0; j < 4; ++j) {
            tok[j] = row_token[r0 + lr + j];
            cf[j]  = row_coef[r0 + lr + j];
        }
#pragma unroll
        for (int n = 0; n < 4; ++n) {
            const int f = cb + wc + n * 16 + fr;
            const float bias = bexp[(size_t)e * HD + f];
#pragma unroll
            for (int j = 0; j < 4; ++j) {
                if (tok[j] >= 0)
                    atomicAdd(&out[(size_t)tok[j] * HD + f], (acc[m][n][j] + bias) * cf[j]);
            }
        }
    }
}

// ---------------------------------------------------------------------------
extern "C" void kernel_launch(void* const* d_in, const int* in_sizes, int n_in,
                              void* d_out, int out_size, void* d_ws, size_t ws_size,
                              hipStream_t stream)
{
    (void)in_sizes; (void)n_in; (void)out_size;

    const float* x  = (const float*)d_in[0];
    const float* Wg = (const float*)d_in[1];
    const float* bg = (const float*)d_in[2];
    const float* W  = (const float*)d_in[3];
    const float* b  = (const float*)d_in[4];

    float* out    = (float*)d_out;
    float* logits = out + (size_t)T_TOK * HD;

    // workspace layout
    char* p = (char*)d_ws;
    int*   cnt       = (int*)p;   p += NE * 4;
    int*   cursor    = (int*)p;   p += NE * 4;
    int*   ntiles    = (int*)p;   p += 8;
    int*   tile_exp  = (int*)p;   p += MAXT * 4;
    int*   tile_row0 = (int*)p;   p += MAXT * 4;
    int*   tok_exp   = (int*)p;   p += T_TOK * 2 * 4;
    float* tok_w     = (float*)p; p += T_TOK * 2 * 4;
    int*   row_token = (int*)p;   p += RMAX * 4;
    float* row_coef  = (float*)p; p += RMAX * 4;
    p = (char*)(((size_t)p + 255) & ~(size_t)255);
    __bf16* xb = (__bf16*)p;      p += (size_t)T_TOK * HD * 2;     // 33.5 MB
    __bf16* Wt = (__bf16*)p;      p += (size_t)NE * HD * HD * 2;   // 67.1 MB
    const bool fast = ws_size >= (size_t)(p - (char*)d_ws);

    hipMemsetAsync(cnt, 0, NE * 4, stream);
    hipMemsetAsync(row_token, 0xFF, RMAX * 4, stream);             // -1 fill
    hipMemsetAsync(out, 0, (size_t)T_TOK * HD * sizeof(float), stream);

    router_kernel<<<T_TOK / 4, 256, 0, stream>>>(x, Wg, bg, logits, cnt, tok_exp, tok_w);
    scan_kernel<<<1, 64, 0, stream>>>(cnt, cursor, tile_exp, tile_row0, ntiles);
    scatter_kernel<<<T_TOK / 256, 256, 0, stream>>>(tok_exp, tok_w, cursor, row_token, row_coef);

    dim3 grid(HD / BN, MAXT);
    if (fast) {
        cvt_x_kernel<<<(T_TOK * HD) / (256 * 8), 256, 0, stream>>>(x, xb);
        wt_kernel<<<dim3(HD / 64, HD / 64, NE), 256, 0, stream>>>(W, Wt);
        moe_gemm_fast<<<grid, 256, 0, stream>>>(xb, Wt, b, tile_exp, tile_row0, ntiles,
                                                row_token, row_coef, out);
    } else {
        moe_gemm<<<grid, 256, 0, stream>>>(x, W, b, tile_exp, tile_row0, ntiles,
                                           row_token, row_coef, out);
    }
}

// Round 3
// 647.760 us; speedup vs baseline: 1.7638x; 1.0410x over previous
//
#include <hip/hip_runtime.h>
#include <math.h>

#define T_TOK 8192
#define HD    2048
#define NE    8
#define BM    256
#define BN    256
#define MAXT  72             // max row-tiles: 16384/256 + 8 pad tiles
#define RMAX  18432          // 72 * 256

typedef __bf16 bf16x8 __attribute__((ext_vector_type(8)));
typedef float  f32x4  __attribute__((ext_vector_type(4)));

// 16B async global->LDS. LDS dest is wave-uniform base + lane*16 (linear);
// per-lane GLOBAL source carries the swizzle (rule 21: linear dest +
// inverse-swizzled source + swizzled read).
#define GLOAD16(src, dst)                                                              \
    __builtin_amdgcn_global_load_lds((__attribute__((address_space(1))) void*)(src),   \
                                     (__attribute__((address_space(3))) void*)(dst),   \
                                     16, 0, 0)

// ---------------------------------------------------------------------------
// Router: one wave per token. fp32 logits (exact), top-2, renormalized weights.
// ---------------------------------------------------------------------------
__global__ __launch_bounds__(256) void router_kernel(
    const float* __restrict__ x, const float* __restrict__ Wg,
    const float* __restrict__ bg, float* __restrict__ logits_out,
    int* __restrict__ cnt, int* __restrict__ tok_exp, float* __restrict__ tok_w)
{
    const int lane = threadIdx.x & 63;
    const int wv   = threadIdx.x >> 6;
    const int t    = blockIdx.x * 4 + wv;
    const float* xr = x + (size_t)t * HD;

    float acc[8] = {0.f,0.f,0.f,0.f,0.f,0.f,0.f,0.f};
    for (int h0 = 0; h0 < HD; h0 += 64) {
        float xv = xr[h0 + lane];
        const float4* wg = reinterpret_cast<const float4*>(Wg + (size_t)(h0 + lane) * NE);
        float4 wa = wg[0], wb = wg[1];
        acc[0] += xv * wa.x; acc[1] += xv * wa.y;
        acc[2] += xv * wa.z; acc[3] += xv * wa.w;
        acc[4] += xv * wb.x; acc[5] += xv * wb.y;
        acc[6] += xv * wb.z; acc[7] += xv * wb.w;
    }
#pragma unroll
    for (int off = 32; off; off >>= 1) {
#pragma unroll
        for (int e = 0; e < 8; ++e) acc[e] += __shfl_xor(acc[e], off);
    }
    if (lane == 0) {
        float lg[8];
#pragma unroll
        for (int e = 0; e < 8; ++e) lg[e] = acc[e] + bg[e];
        float4* lo = reinterpret_cast<float4*>(logits_out + (size_t)t * NE);
        lo[0] = make_float4(lg[0], lg[1], lg[2], lg[3]);
        lo[1] = make_float4(lg[4], lg[5], lg[6], lg[7]);
        int i0 = 0;
        for (int e = 1; e < 8; ++e) if (lg[e] > lg[i0]) i0 = e;
        int i1 = (i0 == 0) ? 1 : 0;
        for (int e = 0; e < 8; ++e) if (e != i0 && lg[e] > lg[i1]) i1 = e;
        float d = expf(lg[i1] - lg[i0]);
        float inv = 1.0f / (1.0f + d);
        tok_exp[t * 2]     = i0;
        tok_exp[t * 2 + 1] = i1;
        tok_w[t * 2]       = inv;
        tok_w[t * 2 + 1]   = d * inv;
        atomicAdd(&cnt[i0], 1);
        atomicAdd(&cnt[i1], 1);
    }
}

// ---------------------------------------------------------------------------
// x fp32 -> bf16 (linear copy)
// ---------------------------------------------------------------------------
__global__ __launch_bounds__(256) void cvt_x_kernel(const float* __restrict__ x,
                                                    __bf16* __restrict__ xb)
{
    size_t i = ((size_t)blockIdx.x * 256 + threadIdx.x) * 8;
    const float4* p = reinterpret_cast<const float4*>(x + i);
    float4 a = p[0], b = p[1];
    bf16x8 v;
    v[0]=(__bf16)a.x; v[1]=(__bf16)a.y; v[2]=(__bf16)a.z; v[3]=(__bf16)a.w;
    v[4]=(__bf16)b.x; v[5]=(__bf16)b.y; v[6]=(__bf16)b.z; v[7]=(__bf16)b.w;
    *reinterpret_cast<bf16x8*>(xb + i) = v;
}

// ---------------------------------------------------------------------------
// W[e][k][f] fp32 -> Wt[e][f][k] bf16. 64x64 tile via padded fp32 LDS [64][65]:
// conflict-free writes (same k, f spread across banks) and reads (k*65 walks
// banks at stride 1).
// ---------------------------------------------------------------------------
__global__ __launch_bounds__(256) void wt_kernel(const float* __restrict__ W,
                                                 __bf16* __restrict__ Wt)
{
    const int e  = blockIdx.z;
    const int k0 = blockIdx.y * 64;
    const int f0 = blockIdx.x * 64;
    __shared__ float T[64][65];

    const int t  = threadIdx.x;
    const int fi = (t & 15) * 4;
    const int kb = t >> 4;                   // 0..15
    const float* src = W + (size_t)e * HD * HD + (size_t)(k0 + kb) * HD + f0 + fi;
#pragma unroll
    for (int j = 0; j < 4; ++j) {
        float4 v = *reinterpret_cast<const float4*>(src + (size_t)j * 16 * HD);
        int k = kb + j * 16;
        T[k][fi + 0] = v.x;
        T[k][fi + 1] = v.y;
        T[k][fi + 2] = v.z;
        T[k][fi + 3] = v.w;
    }
    __syncthreads();
    const int f  = t >> 2;                   // 0..63
    const int kc = (t & 3) * 16;             // 0,16,32,48
    bf16x8 o0, o1;
#pragma unroll
    for (int j = 0; j < 8; ++j) o0[j] = (__bf16)T[kc + j][f];
#pragma unroll
    for (int j = 0; j < 8; ++j) o1[j] = (__bf16)T[kc + 8 + j][f];
    __bf16* dst = Wt + (size_t)e * HD * HD + (size_t)(f0 + f) * HD + k0 + kc;
    *reinterpret_cast<bf16x8*>(dst)     = o0;
    *reinterpret_cast<bf16x8*>(dst + 8) = o1;
}

// ---------------------------------------------------------------------------
// Scan: per-expert offsets padded to 256, tile table, init cursors.
// (row_token pre-filled to -1 via hipMemsetAsync(0xFF))
// ---------------------------------------------------------------------------
__global__ void scan_kernel(const int* __restrict__ cnt, int* __restrict__ cursor,
                            int* __restrict__ tile_exp, int* __restrict__ tile_row0,
                            int* __restrict__ ntiles)
{
    if (threadIdx.x == 0) {
        int off = 0, nt = 0;
        for (int e = 0; e < NE; ++e) {
            cursor[e] = off;
            int c = cnt[e];
            int tiles = (c + 255) >> 8;
            for (int i = 0; i < tiles; ++i) {
                tile_exp[nt]  = e;
                tile_row0[nt] = off + (i << 8);
                ++nt;
            }
            off += tiles << 8;
        }
        *ntiles = nt;
    }
}

// ---------------------------------------------------------------------------
// Scatter: (token, slot) -> permuted row arrays (order-independent results:
// per-row GEMM identical; 2-way fp atomic combine is commutative).
// ---------------------------------------------------------------------------
__global__ __launch_bounds__(256) void scatter_kernel(
    const int* __restrict__ tok_exp, const float* __restrict__ tok_w,
    int* __restrict__ cursor, int* __restrict__ row_token, float* __restrict__ row_coef)
{
    int t = blockIdx.x * blockDim.x + threadIdx.x;
    if (t >= T_TOK) return;
#pragma unroll
    for (int k = 0; k < 2; ++k) {
        int e = tok_exp[t * 2 + k];
        int pos = atomicAdd(&cursor[e], 1);
        row_token[pos] = t;
        row_coef[pos]  = tok_w[t * 2 + k];
    }
}

// ---------------------------------------------------------------------------
// Grouped GEMM, 256x256 tile, 8 waves (2M x 4N), BK=64, double-buffered LDS
// (128 KB), 2-phase schedule: issue next-tile global_load_lds BEFORE compute,
// one barrier per K-step. XOR bank-swizzle via pre-swizzled global source.
// Epilogue: (acc + bias) * coef, atomicAdd combine (2 adds/element).
// ---------------------------------------------------------------------------
__global__ __launch_bounds__(512, 2) void moe_gemm_256(
    const __bf16* __restrict__ xb, const __bf16* __restrict__ Wt,
    const float* __restrict__ bexp,
    const int* __restrict__ tile_exp, const int* __restrict__ tile_row0,
    const int* __restrict__ ntiles_p, const int* __restrict__ row_token,
    const float* __restrict__ row_coef, float* __restrict__ out)
{
    const int rt = blockIdx.y;
    if (rt >= *ntiles_p) return;
    const int e  = tile_exp[rt];
    const int r0 = tile_row0[rt];
    const int cb = blockIdx.x * BN;

    // buf c at c*65536: A [256][64]bf16 (32K) then B [256][64]bf16 (32K)
    __shared__ __align__(16) char lds[131072];

    const int tid  = threadIdx.x;
    const int lane = tid & 63;
    const int wv   = tid >> 6;          // 0..7
    const int wm   = wv >> 2;           // 0..1  (M half)
    const int wn   = wv & 3;            // 0..3  (N quarter)

    // staging: issue i covers tile rows i*64 + wv*8 + (lane>>3); source column
    // pre-swizzled so linear LDS dest + swizzled read = bank-conflict-free.
    const int colS = ((((lane & 7) * 16) ^ ((lane >> 3) << 4))) >> 1;  // bf16 elems

    const __bf16* srcA[4];
    const __bf16* srcB[4];
#pragma unroll
    for (int i = 0; i < 4; ++i) {
        int gr  = i * 64 + wv * 8 + (lane >> 3);
        int tok = row_token[r0 + gr];
        if (tok < 0) tok = 0;           // pad rows: arbitrary data, discarded later
        srcA[i] = xb + (size_t)tok * HD + colS;
        srcB[i] = Wt + ((size_t)e << 22) + (size_t)(cb + gr) * HD + colS;
    }

    f32x4 acc[8][4];
#pragma unroll
    for (int m = 0; m < 8; ++m)
#pragma unroll
        for (int n = 0; n < 4; ++n) acc[m][n] = (f32x4){0.f, 0.f, 0.f, 0.f};

    const int fr    = lane & 15;
    const int swz   = (lane & 7) << 4;
    const int koff0 = (((lane >> 4) * 16)      ) ^ swz;   // ks=0 k-byte, swizzled
    const int koff1 = (((lane >> 4) * 16) + 64 ) ^ swz;   // ks=1

    // prologue: stage K-tile 0 into buf 0
    {
        char* dA = lds + wv * 1024;
        char* dB = lds + 32768 + wv * 1024;
#pragma unroll
        for (int i = 0; i < 4; ++i) GLOAD16(srcA[i], dA + i * 8192);
#pragma unroll
        for (int i = 0; i < 4; ++i) GLOAD16(srcB[i], dB + i * 8192);
    }
    __syncthreads();

    int cur = 0;
    for (int t = 0; t < HD / 64; ++t) {
        // issue next K-tile into the other buffer (lands before next barrier)
        if (t < HD / 64 - 1) {
            const int nk = (t + 1) * 64;
            char* dA = lds + (cur ^ 1) * 65536 + wv * 1024;
            char* dB = dA + 32768;
#pragma unroll
            for (int i = 0; i < 4; ++i) GLOAD16(srcA[i] + nk, dA + i * 8192);
#pragma unroll
            for (int i = 0; i < 4; ++i) GLOAD16(srcB[i] + nk, dB + i * 8192);
        }
        const char* ab = lds + cur * 65536;
        const char* bb = ab + 32768;

        bf16x8 bfr0[4], bfr1[4];
#pragma unroll
        for (int n = 0; n < 4; ++n) {
            int rowb = (wn * 64 + n * 16 + fr) << 7;
            bfr0[n] = *reinterpret_cast<const bf16x8*>(bb + (rowb + koff0));
            bfr1[n] = *reinterpret_cast<const bf16x8*>(bb + (rowb + koff1));
        }
        __builtin_amdgcn_s_setprio(1);
#pragma unroll
        for (int m = 0; m < 8; ++m) {
            int rowa = (wm * 128 + m * 16 + fr) << 7;
            bf16x8 a0 = *reinterpret_cast<const bf16x8*>(ab + (rowa + koff0));
            bf16x8 a1 = *reinterpret_cast<const bf16x8*>(ab + (rowa + koff1));
#pragma unroll
            for (int n = 0; n < 4; ++n) {
                acc[m][n] = __builtin_amdgcn_mfma_f32_16x16x32_bf16(a0, bfr0[n], acc[m][n], 0, 0, 0);
                acc[m][n] = __builtin_amdgcn_mfma_f32_16x16x32_bf16(a1, bfr1[n], acc[m][n], 0, 0, 0);
            }
        }
        __builtin_amdgcn_s_setprio(0);
        __syncthreads();    // drains vmcnt(0)+lgkmcnt(0): next buf landed,
                            // this buf's reads done before it's overwritten
        cur ^= 1;
    }

    // epilogue: (acc + bias) * coef, atomic combine (exactly 2 adds/element)
    const int rj = (lane >> 4) * 4;
    float bias_[4];
#pragma unroll
    for (int n = 0; n < 4; ++n)
        bias_[n] = bexp[(size_t)e * HD + cb + wn * 64 + n * 16 + fr];

#pragma unroll
    for (int m = 0; m < 8; ++m) {
        const int lr = wm * 128 + m * 16 + rj;
        int tok[4]; float cf[4];
#pragma unroll
        for (int j = 0; j < 4; ++j) {
            tok[j] = row_token[r0 + lr + j];
            cf[j]  = row_coef[r0 + lr + j];
        }
#pragma unroll
        for (int n = 0; n < 4; ++n) {
            const int f = cb + wn * 64 + n * 16 + fr;
#pragma unroll
            for (int j = 0; j < 4; ++j) {
                if (tok[j] >= 0)
                    atomicAdd(&out[(size_t)tok[j] * HD + f], (acc[m][n][j] + bias_[n]) * cf[j]);
            }
        }
    }
}

// ---------------------------------------------------------------------------
extern "C" void kernel_launch(void* const* d_in, const int* in_sizes, int n_in,
                              void* d_out, int out_size, void* d_ws, size_t ws_size,
                              hipStream_t stream)
{
    (void)in_sizes; (void)n_in; (void)out_size; (void)ws_size;

    const float* x  = (const float*)d_in[0];
    const float* Wg = (const float*)d_in[1];
    const float* bg = (const float*)d_in[2];
    const float* W  = (const float*)d_in[3];
    const float* b  = (const float*)d_in[4];

    float* out    = (float*)d_out;
    float* logits = out + (size_t)T_TOK * HD;

    // workspace layout (~101 MB; proven sufficient in round 2)
    char* p = (char*)d_ws;
    int*   cnt       = (int*)p;   p += NE * 4;
    int*   cursor    = (int*)p;   p += NE * 4;
    int*   ntiles    = (int*)p;   p += 8;
    int*   tile_exp  = (int*)p;   p += MAXT * 4;
    int*   tile_row0 = (int*)p;   p += MAXT * 4;
    int*   tok_exp   = (int*)p;   p += T_TOK * 2 * 4;
    float* tok_w     = (float*)p; p += T_TOK * 2 * 4;
    int*   row_token = (int*)p;   p += RMAX * 4;
    float* row_coef  = (float*)p; p += RMAX * 4;
    p = (char*)(((size_t)p + 255) & ~(size_t)255);
    __bf16* xb = (__bf16*)p;      p += (size_t)T_TOK * HD * 2;     // 33.5 MB
    __bf16* Wt = (__bf16*)p;      p += (size_t)NE * HD * HD * 2;   // 67.1 MB

    hipMemsetAsync(cnt, 0, NE * 4, stream);
    hipMemsetAsync(row_token, 0xFF, RMAX * 4, stream);             // -1 fill
    hipMemsetAsync(out, 0, (size_t)T_TOK * HD * sizeof(float), stream);

    router_kernel<<<T_TOK / 4, 256, 0, stream>>>(x, Wg, bg, logits, cnt, tok_exp, tok_w);
    cvt_x_kernel<<<(T_TOK * HD) / (256 * 8), 256, 0, stream>>>(x, xb);
    wt_kernel<<<dim3(HD / 64, HD / 64, NE), 256, 0, stream>>>(W, Wt);
    scan_kernel<<<1, 64, 0, stream>>>(cnt, cursor, tile_exp, tile_row0, ntiles);
    scatter_kernel<<<T_TOK / 256, 256, 0, stream>>>(tok_exp, tok_w, cursor, row_token, row_coef);

    dim3 grid(HD / BN, MAXT);
    moe_gemm_256<<<grid, 512, 0, stream>>>(xb, Wt, b, tile_exp, tile_row0, ntiles,
                                           row_token, row_coef, out);
}

// Round 4
// 579.500 us; speedup vs baseline: 1.9716x; 1.1178x over previous
//
#include <hip/hip_runtime.h>
#include <math.h>

#define T_TOK 8192
#define HD    2048
#define NE    8
#define BM    256
#define BN    256
#define MAXT  72             // max row-tiles: 16384/256 + 8 pad tiles
#define RMAX  18432          // 72 * 256

typedef __bf16 bf16x4 __attribute__((ext_vector_type(4)));
typedef __bf16 bf16x8 __attribute__((ext_vector_type(8)));
typedef float  f32x4  __attribute__((ext_vector_type(4)));

// 16B async global->LDS. LDS dest is wave-uniform base + lane*16 (linear);
// per-lane GLOBAL source carries the swizzle (rule 21: linear dest +
// inverse-swizzled source + swizzled read).
#define GLOAD16(src, dst)                                                              \
    __builtin_amdgcn_global_load_lds((__attribute__((address_space(1))) void*)(src),   \
                                     (__attribute__((address_space(3))) void*)(dst),   \
                                     16, 0, 0)

// ---------------------------------------------------------------------------
// Router + x->bf16 conversion fused: one wave per token. fp32 logits (exact),
// top-2, renormalized weights; also emits xb (bf16 copy of x).
// ---------------------------------------------------------------------------
__global__ __launch_bounds__(256) void router_cvt_kernel(
    const float* __restrict__ x, const float* __restrict__ Wg,
    const float* __restrict__ bg, float* __restrict__ logits_out,
    int* __restrict__ cnt, int* __restrict__ tok_exp, float* __restrict__ tok_w,
    __bf16* __restrict__ xb)
{
    const int lane = threadIdx.x & 63;
    const int wv   = threadIdx.x >> 6;
    const int t    = blockIdx.x * 4 + wv;
    const float* xr  = x  + (size_t)t * HD;
    __bf16*      xbr = xb + (size_t)t * HD;

    float acc[8] = {0.f,0.f,0.f,0.f,0.f,0.f,0.f,0.f};
#pragma unroll
    for (int j = 0; j < 8; ++j) {
        const int h0 = j * 256 + lane * 4;
        float4 xv = *reinterpret_cast<const float4*>(xr + h0);
        bf16x4 bv;
        bv[0] = (__bf16)xv.x; bv[1] = (__bf16)xv.y;
        bv[2] = (__bf16)xv.z; bv[3] = (__bf16)xv.w;
        *reinterpret_cast<bf16x4*>(xbr + h0) = bv;

        const float4* wg = reinterpret_cast<const float4*>(Wg + (size_t)h0 * NE);
        float xs[4] = {xv.x, xv.y, xv.z, xv.w};
#pragma unroll
        for (int r = 0; r < 4; ++r) {
            float4 wa = wg[r * 2], wb = wg[r * 2 + 1];
            acc[0] += xs[r] * wa.x; acc[1] += xs[r] * wa.y;
            acc[2] += xs[r] * wa.z; acc[3] += xs[r] * wa.w;
            acc[4] += xs[r] * wb.x; acc[5] += xs[r] * wb.y;
            acc[6] += xs[r] * wb.z; acc[7] += xs[r] * wb.w;
        }
    }
#pragma unroll
    for (int off = 32; off; off >>= 1) {
#pragma unroll
        for (int e = 0; e < 8; ++e) acc[e] += __shfl_xor(acc[e], off);
    }
    if (lane == 0) {
        float lg[8];
#pragma unroll
        for (int e = 0; e < 8; ++e) lg[e] = acc[e] + bg[e];
        float4* lo = reinterpret_cast<float4*>(logits_out + (size_t)t * NE);
        lo[0] = make_float4(lg[0], lg[1], lg[2], lg[3]);
        lo[1] = make_float4(lg[4], lg[5], lg[6], lg[7]);
        int i0 = 0;
        for (int e = 1; e < 8; ++e) if (lg[e] > lg[i0]) i0 = e;
        int i1 = (i0 == 0) ? 1 : 0;
        for (int e = 0; e < 8; ++e) if (e != i0 && lg[e] > lg[i1]) i1 = e;
        float d = expf(lg[i1] - lg[i0]);
        float inv = 1.0f / (1.0f + d);
        tok_exp[t * 2]     = i0;
        tok_exp[t * 2 + 1] = i1;
        tok_w[t * 2]       = inv;
        tok_w[t * 2 + 1]   = d * inv;
        atomicAdd(&cnt[i0], 1);
        atomicAdd(&cnt[i1], 1);
    }
}

// ---------------------------------------------------------------------------
// W[e][k][f] fp32 -> Wt[e][f][k] bf16. 64x64 tile via padded fp32 LDS [64][65]:
// conflict-free both directions.
// ---------------------------------------------------------------------------
__global__ __launch_bounds__(256) void wt_kernel(const float* __restrict__ W,
                                                 __bf16* __restrict__ Wt)
{
    const int e  = blockIdx.z;
    const int k0 = blockIdx.y * 64;
    const int f0 = blockIdx.x * 64;
    __shared__ float T[64][65];

    const int t  = threadIdx.x;
    const int fi = (t & 15) * 4;
    const int kb = t >> 4;                   // 0..15
    const float* src = W + (size_t)e * HD * HD + (size_t)(k0 + kb) * HD + f0 + fi;
#pragma unroll
    for (int j = 0; j < 4; ++j) {
        float4 v = *reinterpret_cast<const float4*>(src + (size_t)j * 16 * HD);
        int k = kb + j * 16;
        T[k][fi + 0] = v.x;
        T[k][fi + 1] = v.y;
        T[k][fi + 2] = v.z;
        T[k][fi + 3] = v.w;
    }
    __syncthreads();
    const int f  = t >> 2;                   // 0..63
    const int kc = (t & 3) * 16;             // 0,16,32,48
    bf16x8 o0, o1;
#pragma unroll
    for (int j = 0; j < 8; ++j) o0[j] = (__bf16)T[kc + j][f];
#pragma unroll
    for (int j = 0; j < 8; ++j) o1[j] = (__bf16)T[kc + 8 + j][f];
    __bf16* dst = Wt + (size_t)e * HD * HD + (size_t)(f0 + f) * HD + k0 + kc;
    *reinterpret_cast<bf16x8*>(dst)     = o0;
    *reinterpret_cast<bf16x8*>(dst + 8) = o1;
}

// ---------------------------------------------------------------------------
// Scan: per-expert offsets padded to 256, tile table, init cursors.
// (row_token pre-filled to -1 via hipMemsetAsync(0xFF))
// ---------------------------------------------------------------------------
__global__ void scan_kernel(const int* __restrict__ cnt, int* __restrict__ cursor,
                            int* __restrict__ tile_exp, int* __restrict__ tile_row0,
                            int* __restrict__ ntiles)
{
    if (threadIdx.x == 0) {
        int off = 0, nt = 0;
        for (int e = 0; e < NE; ++e) {
            cursor[e] = off;
            int c = cnt[e];
            int tiles = (c + 255) >> 8;
            for (int i = 0; i < tiles; ++i) {
                tile_exp[nt]  = e;
                tile_row0[nt] = off + (i << 8);
                ++nt;
            }
            off += tiles << 8;
        }
        *ntiles = nt;
    }
}

// ---------------------------------------------------------------------------
// Scatter: (token, slot) -> permuted row arrays (order-independent results:
// per-row GEMM identical; 2-way fp atomic combine is commutative).
// ---------------------------------------------------------------------------
__global__ __launch_bounds__(256) void scatter_kernel(
    const int* __restrict__ tok_exp, const float* __restrict__ tok_w,
    int* __restrict__ cursor, int* __restrict__ row_token, float* __restrict__ row_coef)
{
    int t = blockIdx.x * blockDim.x + threadIdx.x;
    if (t >= T_TOK) return;
#pragma unroll
    for (int k = 0; k < 2; ++k) {
        int e = tok_exp[t * 2 + k];
        int pos = atomicAdd(&cursor[e], 1);
        row_token[pos] = t;
        row_coef[pos]  = tok_w[t * 2 + k];
    }
}

// ---------------------------------------------------------------------------
// Grouped GEMM, 256x256 tile, 8 waves (2M x 4N), BK=64, double-buffered LDS,
// COUNTED-vmcnt pipeline (T4): prologue stages tiles 0,1; per K-step
//   s_waitcnt vmcnt(8)  -> barrier -> ds_read + 64 MFMA -> lgkmcnt(0)
//   -> barrier -> issue tile t+2 into the buffer just read.
// Loads stay in flight ACROSS barriers (never drain to 0 mid-loop).
// Hazards: vmcnt(8)+rendezvous barrier => all waves' current-tile loads landed;
// overwrite happens only after all-waves lgkm-drain barrier; t=30/31 peeled.
// ---------------------------------------------------------------------------
__global__ __launch_bounds__(512, 1) void moe_gemm_256(
    const __bf16* __restrict__ xb, const __bf16* __restrict__ Wt,
    const float* __restrict__ bexp,
    const int* __restrict__ tile_exp, const int* __restrict__ tile_row0,
    const int* __restrict__ ntiles_p, const int* __restrict__ row_token,
    const float* __restrict__ row_coef, float* __restrict__ out)
{
    const int rt = blockIdx.y;
    if (rt >= *ntiles_p) return;
    const int e  = tile_exp[rt];
    const int r0 = tile_row0[rt];
    const int cb = blockIdx.x * BN;

    // buf c at c*65536: A [256][64]bf16 (32K) then B [256][64]bf16 (32K)
    __shared__ __align__(16) char lds[131072];

    const int tid  = threadIdx.x;
    const int lane = tid & 63;
    const int wv   = tid >> 6;          // 0..7
    const int wm   = wv >> 2;           // 0..1  (M half)
    const int wn   = wv & 3;            // 0..3  (N quarter)

    // source column pre-swizzled so linear LDS dest + swizzled read = no conflicts
    const int colS = ((((lane & 7) * 16) ^ ((lane >> 3) << 4))) >> 1;  // bf16 elems

    const __bf16* srcA[4];
    const __bf16* srcB[4];
#pragma unroll
    for (int i = 0; i < 4; ++i) {
        int gr  = i * 64 + wv * 8 + (lane >> 3);
        int tok = row_token[r0 + gr];
        if (tok < 0) tok = 0;           // pad rows: arbitrary data, discarded later
        srcA[i] = xb + (size_t)tok * HD + colS;
        srcB[i] = Wt + ((size_t)e << 22) + (size_t)(cb + gr) * HD + colS;
    }

    f32x4 acc[8][4];
#pragma unroll
    for (int m = 0; m < 8; ++m)
#pragma unroll
        for (int n = 0; n < 4; ++n) acc[m][n] = (f32x4){0.f, 0.f, 0.f, 0.f};

    const int fr    = lane & 15;
    const int swz   = (lane & 7) << 4;
    const int koff0 = (((lane >> 4) * 16)      ) ^ swz;   // ks=0 k-byte, swizzled
    const int koff1 = (((lane >> 4) * 16) + 64 ) ^ swz;   // ks=1

    // prologue: stage K-tiles 0 and 1 (16 loads in flight)
    {
        char* d0 = lds + wv * 1024;
        char* d1 = d0 + 65536;
#pragma unroll
        for (int i = 0; i < 4; ++i) GLOAD16(srcA[i], d0 + i * 8192);
#pragma unroll
        for (int i = 0; i < 4; ++i) GLOAD16(srcB[i], d0 + 32768 + i * 8192);
#pragma unroll
        for (int i = 0; i < 4; ++i) GLOAD16(srcA[i] + 64, d1 + i * 8192);
#pragma unroll
        for (int i = 0; i < 4; ++i) GLOAD16(srcB[i] + 64, d1 + 32768 + i * 8192);
    }

#pragma unroll 2
    for (int t = 0; t < HD / 64; ++t) {
        if (t < HD / 64 - 1) { asm volatile("s_waitcnt vmcnt(8)" ::: "memory"); }
        else                 { asm volatile("s_waitcnt vmcnt(0)" ::: "memory"); }
        __builtin_amdgcn_s_barrier();

        const char* ab = lds + (t & 1) * 65536;
        const char* bb = ab + 32768;

        bf16x8 bfr0[4], bfr1[4];
#pragma unroll
        for (int n = 0; n < 4; ++n) {
            int rowb = (wn * 64 + n * 16 + fr) << 7;
            bfr0[n] = *reinterpret_cast<const bf16x8*>(bb + (rowb + koff0));
            bfr1[n] = *reinterpret_cast<const bf16x8*>(bb + (rowb + koff1));
        }
        __builtin_amdgcn_s_setprio(1);
#pragma unroll
        for (int m = 0; m < 8; ++m) {
            int rowa = (wm * 128 + m * 16 + fr) << 7;
            bf16x8 a0 = *reinterpret_cast<const bf16x8*>(ab + (rowa + koff0));
            bf16x8 a1 = *reinterpret_cast<const bf16x8*>(ab + (rowa + koff1));
#pragma unroll
            for (int n = 0; n < 4; ++n) {
                acc[m][n] = __builtin_amdgcn_mfma_f32_16x16x32_bf16(a0, bfr0[n], acc[m][n], 0, 0, 0);
                acc[m][n] = __builtin_amdgcn_mfma_f32_16x16x32_bf16(a1, bfr1[n], acc[m][n], 0, 0, 0);
            }
        }
        __builtin_amdgcn_s_setprio(0);

        if (t < HD / 64 - 2) {
            asm volatile("s_waitcnt lgkmcnt(0)" ::: "memory");
            __builtin_amdgcn_s_barrier();
            const int nk = (t + 2) * 64;
            char* dA = lds + (t & 1) * 65536 + wv * 1024;
#pragma unroll
            for (int i = 0; i < 4; ++i) GLOAD16(srcA[i] + nk, dA + i * 8192);
#pragma unroll
            for (int i = 0; i < 4; ++i) GLOAD16(srcB[i] + nk, dA + 32768 + i * 8192);
        }
    }

    // epilogue: (acc + bias) * coef, atomic combine (exactly 2 adds/element)
    const int rj = (lane >> 4) * 4;
    float bias_[4];
#pragma unroll
    for (int n = 0; n < 4; ++n)
        bias_[n] = bexp[(size_t)e * HD + cb + wn * 64 + n * 16 + fr];

#pragma unroll
    for (int m = 0; m < 8; ++m) {
        const int lr = wm * 128 + m * 16 + rj;
        int tok[4]; float cf[4];
#pragma unroll
        for (int j = 0; j < 4; ++j) {
            tok[j] = row_token[r0 + lr + j];
            cf[j]  = row_coef[r0 + lr + j];
        }
#pragma unroll
        for (int n = 0; n < 4; ++n) {
            const int f = cb + wn * 64 + n * 16 + fr;
#pragma unroll
            for (int j = 0; j < 4; ++j) {
                if (tok[j] >= 0)
                    atomicAdd(&out[(size_t)tok[j] * HD + f], (acc[m][n][j] + bias_[n]) * cf[j]);
            }
        }
    }
}

// ---------------------------------------------------------------------------
extern "C" void kernel_launch(void* const* d_in, const int* in_sizes, int n_in,
                              void* d_out, int out_size, void* d_ws, size_t ws_size,
                              hipStream_t stream)
{
    (void)in_sizes; (void)n_in; (void)out_size; (void)ws_size;

    const float* x  = (const float*)d_in[0];
    const float* Wg = (const float*)d_in[1];
    const float* bg = (const float*)d_in[2];
    const float* W  = (const float*)d_in[3];
    const float* b  = (const float*)d_in[4];

    float* out    = (float*)d_out;
    float* logits = out + (size_t)T_TOK * HD;

    // workspace layout (~101 MB; proven sufficient)
    char* p = (char*)d_ws;
    int*   cnt       = (int*)p;   p += NE * 4;
    int*   cursor    = (int*)p;   p += NE * 4;
    int*   ntiles    = (int*)p;   p += 8;
    int*   tile_exp  = (int*)p;   p += MAXT * 4;
    int*   tile_row0 = (int*)p;   p += MAXT * 4;
    int*   tok_exp   = (int*)p;   p += T_TOK * 2 * 4;
    float* tok_w     = (float*)p; p += T_TOK * 2 * 4;
    int*   row_token = (int*)p;   p += RMAX * 4;
    float* row_coef  = (float*)p; p += RMAX * 4;
    p = (char*)(((size_t)p + 255) & ~(size_t)255);
    __bf16* xb = (__bf16*)p;      p += (size_t)T_TOK * HD * 2;     // 33.5 MB
    __bf16* Wt = (__bf16*)p;      p += (size_t)NE * HD * HD * 2;   // 67.1 MB

    hipMemsetAsync(cnt, 0, NE * 4, stream);
    hipMemsetAsync(row_token, 0xFF, RMAX * 4, stream);             // -1 fill
    hipMemsetAsync(out, 0, (size_t)T_TOK * HD * sizeof(float), stream);

    router_cvt_kernel<<<T_TOK / 4, 256, 0, stream>>>(x, Wg, bg, logits, cnt,
                                                     tok_exp, tok_w, xb);
    wt_kernel<<<dim3(HD / 64, HD / 64, NE), 256, 0, stream>>>(W, Wt);
    scan_kernel<<<1, 64, 0, stream>>>(cnt, cursor, tile_exp, tile_row0, ntiles);
    scatter_kernel<<<T_TOK / 256, 256, 0, stream>>>(tok_exp, tok_w, cursor, row_token, row_coef);

    dim3 grid(HD / BN, MAXT);
    moe_gemm_256<<<grid, 512, 0, stream>>>(xb, Wt, b, tile_exp, tile_row0, ntiles,
                                           row_token, row_coef, out);
}

// Round 6
// 437.451 us; speedup vs baseline: 2.6118x; 1.3247x over previous
//
#include <hip/hip_runtime.h>
#include <math.h>

#define T_TOK 8192
#define HD    2048
#define NE    8
#define BM    256
#define BN    256
#define NT    (HD / 64)      // 32 K-tiles
#define MAXT  72             // max row-tiles: 16384/256 + 8 pad tiles
#define RMAX  18432          // 72 * 256

typedef __bf16 bf16x4 __attribute__((ext_vector_type(4)));
typedef __bf16 bf16x8 __attribute__((ext_vector_type(8)));
typedef float  f32x4  __attribute__((ext_vector_type(4)));

// 16B async global->LDS. LDS dest is wave-uniform base + lane*16 (linear);
// per-lane GLOBAL source carries the swizzle (rule 21: linear dest +
// inverse-swizzled source + swizzled read).
#define GLOAD16(src, dst)                                                              \
    __builtin_amdgcn_global_load_lds((__attribute__((address_space(1))) void*)(src),   \
                                     (__attribute__((address_space(3))) void*)(dst),   \
                                     16, 0, 0)

// ---------------------------------------------------------------------------
// Router + x->bf16 fused. No global atomics (hist kernel counts instead).
// ---------------------------------------------------------------------------
__global__ __launch_bounds__(256) void router_cvt_kernel(
    const float* __restrict__ x, const float* __restrict__ Wg,
    const float* __restrict__ bg, float* __restrict__ logits_out,
    int* __restrict__ tok_exp, float* __restrict__ tok_w,
    __bf16* __restrict__ xb)
{
    const int lane = threadIdx.x & 63;
    const int wv   = threadIdx.x >> 6;
    const int t    = blockIdx.x * 4 + wv;
    const float* xr  = x  + (size_t)t * HD;
    __bf16*      xbr = xb + (size_t)t * HD;

    float acc[8] = {0.f,0.f,0.f,0.f,0.f,0.f,0.f,0.f};
#pragma unroll
    for (int j = 0; j < 8; ++j) {
        const int h0 = j * 256 + lane * 4;
        float4 xv = *reinterpret_cast<const float4*>(xr + h0);
        bf16x4 bv;
        bv[0] = (__bf16)xv.x; bv[1] = (__bf16)xv.y;
        bv[2] = (__bf16)xv.z; bv[3] = (__bf16)xv.w;
        *reinterpret_cast<bf16x4*>(xbr + h0) = bv;

        const float4* wg = reinterpret_cast<const float4*>(Wg + (size_t)h0 * NE);
        float xs[4] = {xv.x, xv.y, xv.z, xv.w};
#pragma unroll
        for (int r = 0; r < 4; ++r) {
            float4 wa = wg[r * 2], wb = wg[r * 2 + 1];
            acc[0] += xs[r] * wa.x; acc[1] += xs[r] * wa.y;
            acc[2] += xs[r] * wa.z; acc[3] += xs[r] * wa.w;
            acc[4] += xs[r] * wb.x; acc[5] += xs[r] * wb.y;
            acc[6] += xs[r] * wb.z; acc[7] += xs[r] * wb.w;
        }
    }
#pragma unroll
    for (int off = 32; off; off >>= 1) {
#pragma unroll
        for (int e = 0; e < 8; ++e) acc[e] += __shfl_xor(acc[e], off);
    }
    if (lane == 0) {
        float lg[8];
#pragma unroll
        for (int e = 0; e < 8; ++e) lg[e] = acc[e] + bg[e];
        float4* lo = reinterpret_cast<float4*>(logits_out + (size_t)t * NE);
        lo[0] = make_float4(lg[0], lg[1], lg[2], lg[3]);
        lo[1] = make_float4(lg[4], lg[5], lg[6], lg[7]);
        int i0 = 0;
        for (int e = 1; e < 8; ++e) if (lg[e] > lg[i0]) i0 = e;
        int i1 = (i0 == 0) ? 1 : 0;
        for (int e = 0; e < 8; ++e) if (e != i0 && lg[e] > lg[i1]) i1 = e;
        float d = expf(lg[i1] - lg[i0]);
        float inv = 1.0f / (1.0f + d);
        tok_exp[t * 2]     = i0;
        tok_exp[t * 2 + 1] = i1;
        tok_w[t * 2]       = inv;
        tok_w[t * 2 + 1]   = d * inv;
    }
}

// ---------------------------------------------------------------------------
// Histogram: LDS bins, 8 global atomics per block (512 total, no hot-spot).
// ---------------------------------------------------------------------------
__global__ __launch_bounds__(256) void hist_kernel(const int* __restrict__ tok_exp,
                                                   int* __restrict__ cnt)
{
    __shared__ int h[NE];
    if (threadIdx.x < NE) h[threadIdx.x] = 0;
    __syncthreads();
    int s = blockIdx.x * 256 + threadIdx.x;
    atomicAdd(&h[tok_exp[s]], 1);
    __syncthreads();
    if (threadIdx.x < NE) atomicAdd(&cnt[threadIdx.x], h[threadIdx.x]);
}

// ---------------------------------------------------------------------------
// W[e][k][f] fp32 -> Wt[e][f][k] bf16. 64x64 tile via padded fp32 LDS [64][65].
// ---------------------------------------------------------------------------
__global__ __launch_bounds__(256) void wt_kernel(const float* __restrict__ W,
                                                 __bf16* __restrict__ Wt)
{
    const int e  = blockIdx.z;
    const int k0 = blockIdx.y * 64;
    const int f0 = blockIdx.x * 64;
    __shared__ float T[64][65];

    const int t  = threadIdx.x;
    const int fi = (t & 15) * 4;
    const int kb = t >> 4;
    const float* src = W + (size_t)e * HD * HD + (size_t)(k0 + kb) * HD + f0 + fi;
#pragma unroll
    for (int j = 0; j < 4; ++j) {
        float4 v = *reinterpret_cast<const float4*>(src + (size_t)j * 16 * HD);
        int k = kb + j * 16;
        T[k][fi + 0] = v.x;
        T[k][fi + 1] = v.y;
        T[k][fi + 2] = v.z;
        T[k][fi + 3] = v.w;
    }
    __syncthreads();
    const int f  = t >> 2;
    const int kc = (t & 3) * 16;
    bf16x8 o0, o1;
#pragma unroll
    for (int j = 0; j < 8; ++j) o0[j] = (__bf16)T[kc + j][f];
#pragma unroll
    for (int j = 0; j < 8; ++j) o1[j] = (__bf16)T[kc + 8 + j][f];
    __bf16* dst = Wt + (size_t)e * HD * HD + (size_t)(f0 + f) * HD + k0 + kc;
    *reinterpret_cast<bf16x8*>(dst)     = o0;
    *reinterpret_cast<bf16x8*>(dst + 8) = o1;
}

// ---------------------------------------------------------------------------
// Scan: per-expert offsets padded to 256, tile table, init cursors.
// ---------------------------------------------------------------------------
__global__ void scan_kernel(const int* __restrict__ cnt, int* __restrict__ cursor,
                            int* __restrict__ tile_exp, int* __restrict__ tile_row0,
                            int* __restrict__ ntiles)
{
    if (threadIdx.x == 0) {
        int off = 0, nt = 0;
        for (int e = 0; e < NE; ++e) {
            cursor[e] = off;
            int c = cnt[e];
            int tiles = (c + 255) >> 8;
            for (int i = 0; i < tiles; ++i) {
                tile_exp[nt]  = e;
                tile_row0[nt] = off + (i << 8);
                ++nt;
            }
            off += tiles << 8;
        }
        *ntiles = nt;
    }
}

// ---------------------------------------------------------------------------
// Scatter: per-block LDS ranks + ONE cursor reservation per expert per block.
// Order within bucket nondeterministic but results order-independent.
// ---------------------------------------------------------------------------
__global__ __launch_bounds__(256) void scatter_kernel(
    const int* __restrict__ tok_exp, const float* __restrict__ tok_w,
    int* __restrict__ cursor, int* __restrict__ row_token, float* __restrict__ row_coef)
{
    __shared__ int lcnt[NE];
    __shared__ int lbase[NE];
    const int tid = threadIdx.x;
    if (tid < NE) lcnt[tid] = 0;
    __syncthreads();
    const int s = blockIdx.x * 256 + tid;
    const int e = tok_exp[s];
    const int r = atomicAdd(&lcnt[e], 1);          // LDS atomic (fast)
    __syncthreads();
    if (tid < NE) lbase[tid] = atomicAdd(&cursor[tid], lcnt[tid]);
    __syncthreads();
    const int pos = lbase[e] + r;
    row_token[pos] = s >> 1;                        // slot -> token
    row_coef[pos]  = tok_w[s];
}

// ---------------------------------------------------------------------------
// Grouped GEMM, 256x256 tile, 8 waves, BK=64, 4-phase/K-tile schedule.
// Phase (h,g) computes C-quadrant using A-half(h)+B-half(g); each phase
// stages one 16KB half-unit (2 GLOAD16) of the NEXT K-tile in order
// A0,B0,B1,A1. Steady state: vmcnt(6) at P1/P2/P3 (3 half-units in flight).
// TAIL (last K-tile, no stages): vmcnt(4)/(2)/(0) — R5's bug was using
// vmcnt(6) here, which retires only A0 of the 8 outstanding loads (B0/B1/A1
// read unsynchronized -> replay-timing race). In-order vmcnt retirement
// makes 4/2/0 exactly retire {A0,B0}, {B1}, {A1}.
// Steady-state overwrite audit (unchanged): a staged slot's previous LDS
// reader retired >=2 barriers before the overwrite is issued.
// ---------------------------------------------------------------------------
__global__ __launch_bounds__(512, 2) void moe_gemm_256(
    const __bf16* __restrict__ xb, const __bf16* __restrict__ Wt,
    const float* __restrict__ bexp,
    const int* __restrict__ tile_exp, const int* __restrict__ tile_row0,
    const int* __restrict__ ntiles_p, const int* __restrict__ row_token,
    const float* __restrict__ row_coef, float* __restrict__ out)
{
    const int rt = blockIdx.y;
    if (rt >= *ntiles_p) return;
    const int e  = tile_exp[rt];
    const int r0 = tile_row0[rt];
    const int cb = blockIdx.x * BN;

    // parity slot at par*65536: A [256][64]bf16 (32K) then B [256][64]bf16
    __shared__ __align__(16) char lds[131072];

    const int tid  = threadIdx.x;
    const int lane = tid & 63;
    const int wv   = tid >> 6;          // 0..7
    const int wq   = wv >> 2;           // 0..1  (m-group inside quadrant)
    const int wp   = wv & 3;            // 0..3  (n-group inside quadrant)
    const int wvo  = wv * 1024;

    // source column pre-swizzled so linear LDS dest + swizzled read = no conflicts
    const int colS = ((((lane & 7) * 16) ^ ((lane >> 3) << 4))) >> 1;  // bf16 elems

    const __bf16* srcA[4];
    const __bf16* srcB[4];
#pragma unroll
    for (int i = 0; i < 4; ++i) {
        int gr  = i * 64 + wv * 8 + (lane >> 3);
        int tok = row_token[r0 + gr];
        if (tok < 0) tok = 0;           // pad rows: arbitrary data, discarded later
        srcA[i] = xb + (size_t)tok * HD + colS;
        srcB[i] = Wt + ((size_t)e << 22) + (size_t)(cb + gr) * HD + colS;
    }

    f32x4 acc[2][2][4][2];
#pragma unroll
    for (int h = 0; h < 2; ++h)
#pragma unroll
        for (int g = 0; g < 2; ++g)
#pragma unroll
            for (int m = 0; m < 4; ++m)
#pragma unroll
                for (int n = 0; n < 2; ++n) acc[h][g][m][n] = (f32x4){0.f,0.f,0.f,0.f};

    const int fr    = lane & 15;
    const int sw    = (lane & 7) << 4;
    const int k16   = (lane >> 4) * 16;
    const int koff0 = k16 ^ sw;
    const int koff1 = (64 + k16) ^ sw;

    // prologue: stage K-tile 0 into parity 0, unit order A0,B0,B1,A1
    GLOAD16(srcA[0], lds + wvo);
    GLOAD16(srcA[1], lds + 8192 + wvo);
    GLOAD16(srcB[0], lds + 32768 + wvo);
    GLOAD16(srcB[1], lds + 32768 + 8192 + wvo);
    GLOAD16(srcB[2], lds + 32768 + 16384 + wvo);
    GLOAD16(srcB[3], lds + 32768 + 24576 + wvo);
    GLOAD16(srcA[2], lds + 16384 + wvo);
    GLOAD16(srcA[3], lds + 24576 + wvo);

// ST: 1 = stage next tile (waits V1..V3 = "6"); 0 = tail ("4","2","0")
#define K_TILE(PAR, T, ST, V1, V2, V3)                                                  \
    {                                                                                   \
        const char* AB = lds + (PAR) * 65536;                                           \
        const char* BB = AB + 32768;                                                    \
        char* NA = lds + ((PAR) ^ 1) * 65536;                                           \
        char* NB = NA + 32768;                                                          \
        const int nk = ((T) + 1) * 64;                                                  \
        bf16x8 a[4][2], b0[2][2], b1[2][2];                                             \
        /* P1 (h=0,g=0): stage A0(next) */                                              \
        if (ST) { GLOAD16(srcA[0] + nk, NA + wvo); GLOAD16(srcA[1] + nk, NA + 8192 + wvo); } \
        asm volatile("s_waitcnt vmcnt(" V1 ")" ::: "memory");                           \
        __builtin_amdgcn_s_barrier();                                                   \
        __builtin_amdgcn_sched_barrier(0);                                              \
        _Pragma("unroll")                                                               \
        for (int m = 0; m < 4; ++m) {                                                   \
            int rb = (wq * 64 + m * 16 + fr) << 7;                                      \
            a[m][0] = *reinterpret_cast<const bf16x8*>(AB + rb + koff0);                \
            a[m][1] = *reinterpret_cast<const bf16x8*>(AB + rb + koff1);                \
        }                                                                               \
        _Pragma("unroll")                                                               \
        for (int n = 0; n < 2; ++n) {                                                   \
            int rb = (wp * 32 + n * 16 + fr) << 7;                                      \
            b0[n][0] = *reinterpret_cast<const bf16x8*>(BB + rb + koff0);               \
            b0[n][1] = *reinterpret_cast<const bf16x8*>(BB + rb + koff1);               \
        }                                                                               \
        __builtin_amdgcn_s_setprio(1);                                                  \
        _Pragma("unroll")                                                               \
        for (int m = 0; m < 4; ++m)                                                     \
            _Pragma("unroll")                                                           \
            for (int n = 0; n < 2; ++n) {                                               \
                acc[0][0][m][n] = __builtin_amdgcn_mfma_f32_16x16x32_bf16(a[m][0], b0[n][0], acc[0][0][m][n], 0, 0, 0); \
                acc[0][0][m][n] = __builtin_amdgcn_mfma_f32_16x16x32_bf16(a[m][1], b0[n][1], acc[0][0][m][n], 0, 0, 0); \
            }                                                                           \
        __builtin_amdgcn_s_setprio(0);                                                  \
        /* P2 (h=0,g=1): stage B0(next) */                                              \
        if (ST) { GLOAD16(srcB[0] + nk, NB + wvo); GLOAD16(srcB[1] + nk, NB + 8192 + wvo); } \
        asm volatile("s_waitcnt vmcnt(" V2 ")" ::: "memory");                           \
        __builtin_amdgcn_s_barrier();                                                   \
        __builtin_amdgcn_sched_barrier(0);                                              \
        _Pragma("unroll")                                                               \
        for (int n = 0; n < 2; ++n) {                                                   \
            int rb = (128 + wp * 32 + n * 16 + fr) << 7;                                \
            b1[n][0] = *reinterpret_cast<const bf16x8*>(BB + rb + koff0);               \
            b1[n][1] = *reinterpret_cast<const bf16x8*>(BB + rb + koff1);               \
        }                                                                               \
        __builtin_amdgcn_s_setprio(1);                                                  \
        _Pragma("unroll")                                                               \
        for (int m = 0; m < 4; ++m)                                                     \
            _Pragma("unroll")                                                           \
            for (int n = 0; n < 2; ++n) {                                               \
                acc[0][1][m][n] = __builtin_amdgcn_mfma_f32_16x16x32_bf16(a[m][0], b1[n][0], acc[0][1][m][n], 0, 0, 0); \
                acc[0][1][m][n] = __builtin_amdgcn_mfma_f32_16x16x32_bf16(a[m][1], b1[n][1], acc[0][1][m][n], 0, 0, 0); \
            }                                                                           \
        __builtin_amdgcn_s_setprio(0);                                                  \
        /* P3 (h=1,g=0): stage B1(next) */                                              \
        if (ST) { GLOAD16(srcB[2] + nk, NB + 16384 + wvo); GLOAD16(srcB[3] + nk, NB + 24576 + wvo); } \
        asm volatile("s_waitcnt vmcnt(" V3 ")" ::: "memory");                           \
        __builtin_amdgcn_s_barrier();                                                   \
        __builtin_amdgcn_sched_barrier(0);                                              \
        _Pragma("unroll")                                                               \
        for (int m = 0; m < 4; ++m) {                                                   \
            int rb = (128 + wq * 64 + m * 16 + fr) << 7;                                \
            a[m][0] = *reinterpret_cast<const bf16x8*>(AB + rb + koff0);                \
            a[m][1] = *reinterpret_cast<const bf16x8*>(AB + rb + koff1);                \
        }                                                                               \
        __builtin_amdgcn_s_setprio(1);                                                  \
        _Pragma("unroll")                                                               \
        for (int m = 0; m < 4; ++m)                                                     \
            _Pragma("unroll")                                                           \
            for (int n = 0; n < 2; ++n) {                                               \
                acc[1][0][m][n] = __builtin_amdgcn_mfma_f32_16x16x32_bf16(a[m][0], b0[n][0], acc[1][0][m][n], 0, 0, 0); \
                acc[1][0][m][n] = __builtin_amdgcn_mfma_f32_16x16x32_bf16(a[m][1], b0[n][1], acc[1][0][m][n], 0, 0, 0); \
            }                                                                           \
        __builtin_amdgcn_s_setprio(0);                                                  \
        /* P4 (h=1,g=1): stage A1(next); regs only, no wait/barrier */                  \
        if (ST) { GLOAD16(srcA[2] + nk, NA + 16384 + wvo); GLOAD16(srcA[3] + nk, NA + 24576 + wvo); } \
        __builtin_amdgcn_s_setprio(1);                                                  \
        _Pragma("unroll")                                                               \
        for (int m = 0; m < 4; ++m)                                                     \
            _Pragma("unroll")                                                           \
            for (int n = 0; n < 2; ++n) {                                               \
                acc[1][1][m][n] = __builtin_amdgcn_mfma_f32_16x16x32_bf16(a[m][0], b1[n][0], acc[1][1][m][n], 0, 0, 0); \
                acc[1][1][m][n] = __builtin_amdgcn_mfma_f32_16x16x32_bf16(a[m][1], b1[n][1], acc[1][1][m][n], 0, 0, 0); \
            }                                                                           \
        __builtin_amdgcn_s_setprio(0);                                                  \
    }

    for (int t = 0; t < NT - 2; t += 2) {
        K_TILE(0, t,     1, "6", "6", "6")
        K_TILE(1, t + 1, 1, "6", "6", "6")
    }
    K_TILE(0, NT - 2, 1, "6", "6", "6")
    K_TILE(1, NT - 1, 0, "4", "2", "0")     // tail: exact retire counts
#undef K_TILE

    // epilogue: (acc + bias) * coef, atomic combine (exactly 2 adds/element)
    const int rj = (lane >> 4) * 4;
#pragma unroll
    for (int h = 0; h < 2; ++h) {
#pragma unroll
        for (int m = 0; m < 4; ++m) {
            const int lr = h * 128 + wq * 64 + m * 16 + rj;
            int tok[4]; float cf[4];
#pragma unroll
            for (int j = 0; j < 4; ++j) {
                tok[j] = row_token[r0 + lr + j];
                cf[j]  = row_coef[r0 + lr + j];
            }
#pragma unroll
            for (int g = 0; g < 2; ++g) {
#pragma unroll
                for (int n = 0; n < 2; ++n) {
                    const int f = cb + g * 128 + wp * 32 + n * 16 + fr;
                    const float bias = bexp[(size_t)e * HD + f];
#pragma unroll
                    for (int j = 0; j < 4; ++j) {
                        if (tok[j] >= 0)
                            atomicAdd(&out[(size_t)tok[j] * HD + f],
                                      (acc[h][g][m][n][j] + bias) * cf[j]);
                    }
                }
            }
        }
    }
}

// ---------------------------------------------------------------------------
extern "C" void kernel_launch(void* const* d_in, const int* in_sizes, int n_in,
                              void* d_out, int out_size, void* d_ws, size_t ws_size,
                              hipStream_t stream)
{
    (void)in_sizes; (void)n_in; (void)out_size; (void)ws_size;

    const float* x  = (const float*)d_in[0];
    const float* Wg = (const float*)d_in[1];
    const float* bg = (const float*)d_in[2];
    const float* W  = (const float*)d_in[3];
    const float* b  = (const float*)d_in[4];

    float* out    = (float*)d_out;
    float* logits = out + (size_t)T_TOK * HD;

    // workspace layout (~101 MB; proven sufficient)
    char* p = (char*)d_ws;
    int*   cnt       = (int*)p;   p += NE * 4;
    int*   cursor    = (int*)p;   p += NE * 4;
    int*   ntiles    = (int*)p;   p += 8;
    int*   tile_exp  = (int*)p;   p += MAXT * 4;
    int*   tile_row0 = (int*)p;   p += MAXT * 4;
    int*   tok_exp   = (int*)p;   p += T_TOK * 2 * 4;
    float* tok_w     = (float*)p; p += T_TOK * 2 * 4;
    int*   row_token = (int*)p;   p += RMAX * 4;
    float* row_coef  = (float*)p; p += RMAX * 4;
    p = (char*)(((size_t)p + 255) & ~(size_t)255);
    __bf16* xb = (__bf16*)p;      p += (size_t)T_TOK * HD * 2;     // 33.5 MB
    __bf16* Wt = (__bf16*)p;      p += (size_t)NE * HD * HD * 2;   // 67.1 MB

    hipMemsetAsync(cnt, 0, NE * 4, stream);
    hipMemsetAsync(row_token, 0xFF, RMAX * 4, stream);             // -1 fill
    hipMemsetAsync(out, 0, (size_t)T_TOK * HD * sizeof(float), stream);

    router_cvt_kernel<<<T_TOK / 4, 256, 0, stream>>>(x, Wg, bg, logits,
                                                     tok_exp, tok_w, xb);
    wt_kernel<<<dim3(HD / 64, HD / 64, NE), 256, 0, stream>>>(W, Wt);
    hist_kernel<<<T_TOK * 2 / 256, 256, 0, stream>>>(tok_exp, cnt);
    scan_kernel<<<1, 64, 0, stream>>>(cnt, cursor, tile_exp, tile_row0, ntiles);
    scatter_kernel<<<T_TOK * 2 / 256, 256, 0, stream>>>(tok_exp, tok_w, cursor,
                                                        row_token, row_coef);

    dim3 grid(HD / BN, MAXT);
    moe_gemm_256<<<grid, 512, 0, stream>>>(xb, Wt, b, tile_exp, tile_row0, ntiles,
                                           row_token, row_coef, out);
}